// Round 4
// baseline (261.428 us; speedup 1.0000x reference)
//
#include <hip/hip_runtime.h>
#include <math.h>

// STGCN layer: N=50000, E=800000, C_IN=C_OUT=64, T=4, KT=3.
// Round-11: delete the xs prescale kernel; scale by dinv[src] inside gather.
//   zero_tw:   zero degree counts; block 0 also builds Bt[o][k] bf16 + bb=bg+bt
//   fill_xbp:  fused, two block roles:
//              - fill role: 8 edges/thread, 8 independent atomics in flight
//              - pack role: x -> xbp bf16 [t][c] w/ guard rows AND
//                xsr bf16 [c][t] ushort4 (UNSCALED gather table) — both from
//                one x read (round-10: streaming rides fill's idle BW)
//   dinv:      dinv[n] = rsqrt(cnt[n]+1)  (tiny, ~2us; needs final cnt)
//   gather:    round-7 structure (wave per TWO nodes, 8 gathers in flight) but
//              reads UNSCALED xsr and applies fp32 dinv[src] per edge (fma);
//              dinv loads are wave-uniform 4B from 200KB L2-resident table.
//              (rounds 8/9: gather invariant to MLP and footprint -> ~59us is
//               the compulsory 25.6MB x 8-XCD L2-replication fill floor)
//   node:      MFMA GEMM, wave = 16 nodes (4 groups): per ki 8 loads, 16 MFMAs
// All dense math in bf16 MFMA w/ fp32 accum; aggregation in fp32.

#define CAP 64   // max bucket capacity; Poisson(16) max degree ~45

typedef __attribute__((ext_vector_type(8))) short bf16x8;   // 8 bf16 = 4 VGPRs
typedef __attribute__((ext_vector_type(4))) float f32x4;

__device__ __forceinline__ float bf2f(unsigned short u) {
    union { unsigned int i; float f; } c; c.i = ((unsigned int)u) << 16; return c.f;
}
__device__ __forceinline__ unsigned short f2bf(float f) {
    union { float f; unsigned int i; } c; c.f = f;
    return (unsigned short)((c.i + 0x7FFFu + ((c.i >> 16) & 1u)) >> 16);  // RNE
}

// zero cnt across grid; block 0 additionally packs weights:
// Bt[o][k] (bf16): k<64: Wg[k][o]; k=b*64+c (b=1..3): Wt[o][c][b-1]. bb=bg+bt.
__global__ __launch_bounds__(256) void zero_tw_kernel(unsigned* __restrict__ cnt, int N,
                                                      const float* __restrict__ Wg,
                                                      const float* __restrict__ Wt,
                                                      const float* __restrict__ bg,
                                                      const float* __restrict__ bt,
                                                      unsigned short* __restrict__ Bt,
                                                      float* __restrict__ bb) {
    int n = blockIdx.x * 256 + threadIdx.x;
    if (n < N) cnt[n] = 0u;
    if (blockIdx.x == 0) {
        for (int idx = threadIdx.x; idx < 64 * 256; idx += 256) {
            int o = idx >> 8, k = idx & 255;
            float w;
            if (k < 64) w = Wg[k * 64 + o];
            else { int b = k >> 6, c = k & 63; w = Wt[o * 192 + c * 3 + (b - 1)]; }
            Bt[idx] = f2bf(w);
        }
        if (threadIdx.x < 64) bb[threadIdx.x] = bg[threadIdx.x] + bt[threadIdx.x];
    }
}

// Fused fill + pack. Block roles split by blockIdx:
//  [0, FB):       fill — 8 edges/thread, 8 independent atomics, 8 CSR stores.
//  [FB, FB+XB):   pack — wave per node, lane = channel; writes xbp [t][c]
//                 (guard rows t=-1,4) and xsr [c][t] (unscaled bf16).
__global__ __launch_bounds__(256) void fill_xbp_kernel(const int* __restrict__ ei,
                                                       unsigned* __restrict__ cnt,
                                                       int* __restrict__ csr, int E,
                                                       const float* __restrict__ x,
                                                       unsigned short* __restrict__ xbp,
                                                       ushort4* __restrict__ xsr,
                                                       int N, int FB) {
    if ((int)blockIdx.x < FB) {
        int t = blockIdx.x * 256 + threadIdx.x;
        int stride = FB * 256;
        int s[8]; int d[8]; unsigned slot[8];
        #pragma unroll
        for (int k = 0; k < 8; ++k) {
            int e = t + k * stride;
            bool v = (e < E);
            s[k] = v ? ei[e] : -1;       // row 0: src
            d[k] = v ? ei[E + e] : 0;    // row 1: dst
        }
        #pragma unroll
        for (int k = 0; k < 8; ++k)
            slot[k] = (s[k] >= 0) ? atomicAdd(&cnt[d[k]], 1u) : 0u;
        #pragma unroll
        for (int k = 0; k < 8; ++k)
            if (s[k] >= 0 && slot[k] < CAP)
                csr[(size_t)d[k] * CAP + slot[k]] = s[k];
    } else {
        int bid = blockIdx.x - FB;
        int n = (bid * 256 + threadIdx.x) >> 6;
        int lane = threadIdx.x & 63;
        if (n >= N) return;
        float4 v = ((const float4*)x)[(size_t)n * 64 + lane];
        unsigned short* xb = xbp + (size_t)n * 384;
        ushort4 sv;
        sv.x = f2bf(v.x); sv.y = f2bf(v.y);
        sv.z = f2bf(v.z); sv.w = f2bf(v.w);
        xsr[(size_t)n * 64 + lane] = sv;   // unscaled gather table [c][t]
        xb[lane]           = 0;            // t = -1 guard
        xb[64 + lane]      = sv.x;         // t = 0
        xb[128 + lane]     = sv.y;
        xb[192 + lane]     = sv.z;
        xb[256 + lane]     = sv.w;
        xb[320 + lane]     = 0;            // t = 4 guard
    }
}

// dinv[n] = rsqrt(deg[n] + 1). 200KB table, L2-resident for gather.
__global__ __launch_bounds__(256) void dinv_kernel(const unsigned* __restrict__ cnt,
                                                   float* __restrict__ dinv, int N) {
    int n = blockIdx.x * 256 + threadIdx.x;
    if (n < N) dinv[n] = rsqrtf((float)cnt[n] + 1.0f);
}

// Wave per TWO nodes; lane = channel c (ushort4 = t0..3). Interleaved inner
// loop: 2 int4 index loads + 8 dinv loads + 8 independent 512B gathers in
// flight per iter. Per-edge fp32 scale by dinv[src] (add -> fma, same VALU).
__global__ __launch_bounds__(256) void gather_kernel(const ushort4* __restrict__ xsr,
                                                     const int* __restrict__ csr,
                                                     const unsigned* __restrict__ cnt,
                                                     const float* __restrict__ dinv,
                                                     unsigned short* __restrict__ yT,
                                                     int N) {
    int w = (blockIdx.x * 256 + threadIdx.x) >> 6;
    int lane = threadIdx.x & 63;
    int n0 = w * 2;
    if (n0 >= N) return;
    int n1 = n0 + 1;                           // N even
    unsigned deg0 = cnt[n0], deg1 = cnt[n1];
    int m0 = (int)deg0; if (m0 > CAP) m0 = CAP;
    int m1 = (int)deg1; if (m1 > CAP) m1 = CAP;
    const int4* r40 = (const int4*)(csr + (size_t)n0 * CAP);
    const int4* r41 = (const int4*)(csr + (size_t)n1 * CAP);
    float di0 = dinv[n0], di1 = dinv[n1];
    ushort4 s0 = xsr[(size_t)n0 * 64 + lane];
    ushort4 s1 = xsr[(size_t)n1 * 64 + lane];
    float4 acc0 = make_float4(bf2f(s0.x) * di0, bf2f(s0.y) * di0,
                              bf2f(s0.z) * di0, bf2f(s0.w) * di0);
    float4 acc1 = make_float4(bf2f(s1.x) * di1, bf2f(s1.y) * di1,
                              bf2f(s1.z) * di1, bf2f(s1.w) * di1);

    int mc = (m0 < m1 ? m0 : m1) & ~3;
    int i = 0;
    for (; i < mc; i += 4) {                   // interleaved: 8 gathers in flight
        int4 a4 = r40[i >> 2];
        int4 b4 = r41[i >> 2];
        float va = dinv[a4.x], vb = dinv[a4.y], vc = dinv[a4.z], vd = dinv[a4.w];
        float ve = dinv[b4.x], vf = dinv[b4.y], vg = dinv[b4.z], vh = dinv[b4.w];
        ushort4 a = xsr[(size_t)a4.x * 64 + lane];
        ushort4 b = xsr[(size_t)a4.y * 64 + lane];
        ushort4 c = xsr[(size_t)a4.z * 64 + lane];
        ushort4 d = xsr[(size_t)a4.w * 64 + lane];
        ushort4 e = xsr[(size_t)b4.x * 64 + lane];
        ushort4 f = xsr[(size_t)b4.y * 64 + lane];
        ushort4 g = xsr[(size_t)b4.z * 64 + lane];
        ushort4 h = xsr[(size_t)b4.w * 64 + lane];
        acc0.x += (bf2f(a.x) * va + bf2f(b.x) * vb) + (bf2f(c.x) * vc + bf2f(d.x) * vd);
        acc0.y += (bf2f(a.y) * va + bf2f(b.y) * vb) + (bf2f(c.y) * vc + bf2f(d.y) * vd);
        acc0.z += (bf2f(a.z) * va + bf2f(b.z) * vb) + (bf2f(c.z) * vc + bf2f(d.z) * vd);
        acc0.w += (bf2f(a.w) * va + bf2f(b.w) * vb) + (bf2f(c.w) * vc + bf2f(d.w) * vd);
        acc1.x += (bf2f(e.x) * ve + bf2f(f.x) * vf) + (bf2f(g.x) * vg + bf2f(h.x) * vh);
        acc1.y += (bf2f(e.y) * ve + bf2f(f.y) * vf) + (bf2f(g.y) * vg + bf2f(h.y) * vh);
        acc1.z += (bf2f(e.z) * ve + bf2f(f.z) * vf) + (bf2f(g.z) * vg + bf2f(h.z) * vh);
        acc1.w += (bf2f(e.w) * ve + bf2f(f.w) * vf) + (bf2f(g.w) * vg + bf2f(h.w) * vh);
    }
    int j = i;
    for (; i + 4 <= m0; i += 4) {              // node0 remainder quads
        int4 a4 = r40[i >> 2];
        float va = dinv[a4.x], vb = dinv[a4.y], vc = dinv[a4.z], vd = dinv[a4.w];
        ushort4 a = xsr[(size_t)a4.x * 64 + lane];
        ushort4 b = xsr[(size_t)a4.y * 64 + lane];
        ushort4 c = xsr[(size_t)a4.z * 64 + lane];
        ushort4 d = xsr[(size_t)a4.w * 64 + lane];
        acc0.x += (bf2f(a.x) * va + bf2f(b.x) * vb) + (bf2f(c.x) * vc + bf2f(d.x) * vd);
        acc0.y += (bf2f(a.y) * va + bf2f(b.y) * vb) + (bf2f(c.y) * vc + bf2f(d.y) * vd);
        acc0.z += (bf2f(a.z) * va + bf2f(b.z) * vb) + (bf2f(c.z) * vc + bf2f(d.z) * vd);
        acc0.w += (bf2f(a.w) * va + bf2f(b.w) * vb) + (bf2f(c.w) * vc + bf2f(d.w) * vd);
    }
    for (; i < m0; ++i) {
        int s = ((const int*)r40)[i];
        float dv = dinv[s];
        ushort4 a = xsr[(size_t)s * 64 + lane];
        acc0.x += bf2f(a.x) * dv; acc0.y += bf2f(a.y) * dv;
        acc0.z += bf2f(a.z) * dv; acc0.w += bf2f(a.w) * dv;
    }
    for (; j + 4 <= m1; j += 4) {              // node1 remainder quads
        int4 b4 = r41[j >> 2];
        float ve = dinv[b4.x], vf = dinv[b4.y], vg = dinv[b4.z], vh = dinv[b4.w];
        ushort4 e = xsr[(size_t)b4.x * 64 + lane];
        ushort4 f = xsr[(size_t)b4.y * 64 + lane];
        ushort4 g = xsr[(size_t)b4.z * 64 + lane];
        ushort4 h = xsr[(size_t)b4.w * 64 + lane];
        acc1.x += (bf2f(e.x) * ve + bf2f(f.x) * vf) + (bf2f(g.x) * vg + bf2f(h.x) * vh);
        acc1.y += (bf2f(e.y) * ve + bf2f(f.y) * vf) + (bf2f(g.y) * vg + bf2f(h.y) * vh);
        acc1.z += (bf2f(e.z) * ve + bf2f(f.z) * vf) + (bf2f(g.z) * vg + bf2f(h.z) * vh);
        acc1.w += (bf2f(e.w) * ve + bf2f(f.w) * vf) + (bf2f(g.w) * vg + bf2f(h.w) * vh);
    }
    for (; j < m1; ++j) {
        int s = ((const int*)r41)[j];
        float dv = dinv[s];
        ushort4 e = xsr[(size_t)s * 64 + lane];
        acc1.x += bf2f(e.x) * dv; acc1.y += bf2f(e.y) * dv;
        acc1.z += bf2f(e.z) * dv; acc1.w += bf2f(e.w) * dv;
    }

    unsigned short* yp0 = yT + (size_t)n0 * 256;
    unsigned short* yp1 = yT + (size_t)n1 * 256;
    yp0[lane]       = f2bf(acc0.x * di0);      // coalesced 128B rows
    yp0[64 + lane]  = f2bf(acc0.y * di0);
    yp0[128 + lane] = f2bf(acc0.z * di0);
    yp0[192 + lane] = f2bf(acc0.w * di0);
    yp1[lane]       = f2bf(acc1.x * di1);
    yp1[64 + lane]  = f2bf(acc1.y * di1);
    yp1[128 + lane] = f2bf(acc1.z * di1);
    yp1[192 + lane] = f2bf(acc1.w * di1);
}

// MFMA node kernel. Wave = 4 groups x 4 nodes = 16 nodes. Per group: 16 M-rows
// (m = nd*4 + t), K = 256, o = 64 (4 otiles of 16).
// A[(n,t)][k]: k<64 -> yT[n][t][k]; k=b*64+c -> xbp[n][t+b-1][c] (guarded rows).
// A-frag: lane holds A[m=lane&15][k = ki*32 + (lane>>4)*8 + j], 16B contiguous.
// B-frag: lane holds W[k][o = otile*16 + (lane&15)] from Bt[o][k], 16B contiguous.
// C/D: col = lane&15 (=o-idx), row = (lane>>4)*4 + reg -> node +(lane>>4), t = reg.
__global__ __launch_bounds__(256) void node_kernel(const unsigned short* __restrict__ yT,
                                                   const unsigned short* __restrict__ xbp,
                                                   const unsigned short* __restrict__ Bt,
                                                   const float* __restrict__ bb,
                                                   float* __restrict__ out, int N) {
    int wid = (blockIdx.x * 256 + threadIdx.x) >> 6;   // global wave id
    int lane = threadIdx.x & 63;
    int base = wid * 16;                               // first node of this wave
    if (base + 16 > N) return;                         // N % 16 == 0
    int h = lane >> 4;          // quad
    int m = lane & 15;
    int nd = m >> 2, t = m & 3;

    const unsigned short* yp[4];
    const unsigned short* xp[4];
    #pragma unroll
    for (int g = 0; g < 4; ++g) {
        int node = base + g * 4 + nd;
        yp[g] = yT + (size_t)node * 256 + t * 64;
        xp[g] = xbp + (size_t)node * 384 + t * 64;
    }

    f32x4 acc[4][4];
    #pragma unroll
    for (int g = 0; g < 4; ++g)
        #pragma unroll
        for (int ot = 0; ot < 4; ++ot)
            acc[g][ot] = (f32x4){0.f, 0.f, 0.f, 0.f};

    #pragma unroll
    for (int ki = 0; ki < 8; ++ki) {
        int b = ki >> 1;                       // 64-wide K-block
        int c0 = (ki & 1) * 32 + h * 8;        // offset within block
        int kof = ki * 32 + h * 8;
        bf16x8 bf[4];
        #pragma unroll
        for (int ot = 0; ot < 4; ++ot)
            bf[ot] = *(const bf16x8*)(Bt + (size_t)(ot * 16 + m) * 256 + kof);
        bf16x8 af[4];
        #pragma unroll
        for (int g = 0; g < 4; ++g) {
            const unsigned short* ap = (b == 0) ? (yp[g] + c0)
                                                : (xp[g] + (b - 1) * 64 + c0);
            af[g] = *(const bf16x8*)ap;
        }
        #pragma unroll
        for (int g = 0; g < 4; ++g) {
            acc[g][0] = __builtin_amdgcn_mfma_f32_16x16x32_bf16(af[g], bf[0], acc[g][0], 0, 0, 0);
            acc[g][1] = __builtin_amdgcn_mfma_f32_16x16x32_bf16(af[g], bf[1], acc[g][1], 0, 0, 0);
            acc[g][2] = __builtin_amdgcn_mfma_f32_16x16x32_bf16(af[g], bf[2], acc[g][2], 0, 0, 0);
            acc[g][3] = __builtin_amdgcn_mfma_f32_16x16x32_bf16(af[g], bf[3], acc[g][3], 0, 0, 0);
        }
    }

    float4* out4 = (float4*)out;               // out[n][o][t], float4 over t
    #pragma unroll
    for (int g = 0; g < 4; ++g) {
        int nn = base + g * 4 + h;             // output node for this lane
        #pragma unroll
        for (int ot = 0; ot < 4; ++ot) {
            int o = ot * 16 + m;
            float bias = bb[o];
            out4[(size_t)nn * 64 + o] = make_float4(acc[g][ot][0] + bias,
                                                    acc[g][ot][1] + bias,
                                                    acc[g][ot][2] + bias,
                                                    acc[g][ot][3] + bias);
        }
    }
}

extern "C" void kernel_launch(void* const* d_in, const int* in_sizes, int n_in,
                              void* d_out, int out_size, void* d_ws, size_t ws_size,
                              hipStream_t stream) {
    const float* x  = (const float*)d_in[0];
    const int*   ei = (const int*)d_in[1];
    const float* Wg = (const float*)d_in[2];
    const float* bg = (const float*)d_in[3];
    const float* Wt = (const float*)d_in[4];
    const float* bt = (const float*)d_in[5];
    float* out = (float*)d_out;

    int N = in_sizes[0] / 256;   // 50000
    int E = in_sizes[1] / 2;     // 800000

    // workspace layout (256B-aligned):
    size_t off = 0;
    auto alloc = [&](size_t bytes) { size_t o = off; off += (bytes + 255) & ~(size_t)255; return o; };
    char* ws = (char*)d_ws;
    unsigned*       cnt  = (unsigned*)(ws + alloc((size_t)N * 4));
    float*          dinv = (float*)(ws + alloc((size_t)N * 4));
    unsigned short* Bt   = (unsigned short*)(ws + alloc(64 * 256 * 2));
    float*          bb   = (float*)(ws + alloc(64 * 4));
    int*            csr  = (int*)(ws + alloc((size_t)N * CAP * 4));
    ushort4*        xsr  = (ushort4*)(ws + alloc((size_t)N * 256 * 2));
    unsigned short* xbp  = (unsigned short*)(ws + alloc((size_t)N * 384 * 2));
    unsigned short* yT   = (unsigned short*)(ws + alloc((size_t)N * 256 * 2));
    // total ~103 MB

    zero_tw_kernel<<<(N + 255) / 256, 256, 0, stream>>>(cnt, N, Wg, Wt, bg, bt, Bt, bb);
    int FB = (E + 2047) / 2048;                // 391 fill blocks (8 edges/thread)
    int XB = (N + 3) / 4;                      // 12500 pack blocks (wave/node)
    fill_xbp_kernel<<<FB + XB, 256, 0, stream>>>(ei, cnt, csr, E, x, xbp, xsr, N, FB);
    dinv_kernel<<<(N + 255) / 256, 256, 0, stream>>>(cnt, dinv, N);
    int gw = (N + 1) / 2;                      // 25000 waves, 2 nodes each
    gather_kernel<<<(gw + 3) / 4, 256, 0, stream>>>(xsr, csr, cnt, dinv, yT, N);
    int waves = N / 16;                        // 3125
    node_kernel<<<(waves + 3) / 4, 256, 0, stream>>>(yT, xbp, Bt, bb, out, N);
}

// Round 5
// 254.126 us; speedup vs baseline: 1.0287x; 1.0287x over previous
//
#include <hip/hip_runtime.h>
#include <math.h>

// STGCN layer: N=50000, E=800000, C_IN=C_OUT=64, T=4, KT=3.
// Round-12: rebalance streaming (R4 lesson: fill's atomic shadow hides ~90MB
// of streaming, not 115MB) + drop the dinv launch.
//   zero_pack: zero cnt; wave-per-node builds xsr bf16 [c][t] (UNSCALED gather
//              table) from x (cold HBM read); block 0 packs Bt + bb.
//   fill_xbp:  fused, two block roles (exact R3 payload, proven <=59us):
//              - fill role: 8 edges/thread, 8 independent atomics in flight
//              - pack role: x (L3-hot re-read) -> xbp bf16 [t][c] w/ guards
//   gather:    round-7 structure (wave per TWO nodes, 8 gathers in flight),
//              UNSCALED xsr + per-edge dinv = rsqrtf(cnt[src]+1) inline
//              (cnt is 200KB L2-resident; wave-uniform scalar load + v_rsq).
//              (rounds 8/9/2: gather invariant to MLP/footprint/occupancy ->
//               ~59us is the compulsory 25.6MB x 8-XCD L2-replication floor)
//   node:      MFMA GEMM, wave = 16 nodes (4 groups): per ki 8 loads, 16 MFMAs
// All dense math in bf16 MFMA w/ fp32 accum; aggregation in fp32.

#define CAP 64   // max bucket capacity; Poisson(16) max degree ~45

typedef __attribute__((ext_vector_type(8))) short bf16x8;   // 8 bf16 = 4 VGPRs
typedef __attribute__((ext_vector_type(4))) float f32x4;

__device__ __forceinline__ float bf2f(unsigned short u) {
    union { unsigned int i; float f; } c; c.i = ((unsigned int)u) << 16; return c.f;
}
__device__ __forceinline__ unsigned short f2bf(float f) {
    union { float f; unsigned int i; } c; c.f = f;
    return (unsigned short)((c.i + 0x7FFFu + ((c.i >> 16) & 1u)) >> 16);  // RNE
}

// Grid = wave-per-node (12500 blocks). Duties:
//  - thread gid < N: cnt[gid] = 0
//  - wave n: xsr[n][c] = bf16(x[n][c][t0..3]) (unscaled [c][t] ushort4)
//  - block 0: Bt[o][k] (k<64: Wg[k][o]; k=b*64+c: Wt[o][c][b-1]); bb=bg+bt
__global__ __launch_bounds__(256) void zero_pack_kernel(unsigned* __restrict__ cnt, int N,
                                                        const float* __restrict__ Wg,
                                                        const float* __restrict__ Wt,
                                                        const float* __restrict__ bg,
                                                        const float* __restrict__ bt,
                                                        unsigned short* __restrict__ Bt,
                                                        float* __restrict__ bb,
                                                        const float* __restrict__ x,
                                                        ushort4* __restrict__ xsr) {
    int gid = blockIdx.x * 256 + threadIdx.x;
    if (gid < N) cnt[gid] = 0u;
    int n = gid >> 6;
    int lane = threadIdx.x & 63;
    if (n < N) {
        float4 v = ((const float4*)x)[(size_t)n * 64 + lane];
        ushort4 sv;
        sv.x = f2bf(v.x); sv.y = f2bf(v.y);
        sv.z = f2bf(v.z); sv.w = f2bf(v.w);
        xsr[(size_t)n * 64 + lane] = sv;
    }
    if (blockIdx.x == 0) {
        for (int idx = threadIdx.x; idx < 64 * 256; idx += 256) {
            int o = idx >> 8, k = idx & 255;
            float w;
            if (k < 64) w = Wg[k * 64 + o];
            else { int b = k >> 6, c = k & 63; w = Wt[o * 192 + c * 3 + (b - 1)]; }
            Bt[idx] = f2bf(w);
        }
        if (threadIdx.x < 64) bb[threadIdx.x] = bg[threadIdx.x] + bt[threadIdx.x];
    }
}

// Fused fill + xbp pack (R3 payload). Block roles split by blockIdx:
//  [0, FB):       fill — 8 edges/thread, 8 independent atomics, 8 CSR stores.
//  [FB, FB+XB):   pack — wave per node, lane = channel; xbp [t][c] bf16 with
//                 zero guard rows at t=-1 and t=4 (x re-read is L3-hot).
__global__ __launch_bounds__(256) void fill_xbp_kernel(const int* __restrict__ ei,
                                                       unsigned* __restrict__ cnt,
                                                       int* __restrict__ csr, int E,
                                                       const float* __restrict__ x,
                                                       unsigned short* __restrict__ xbp,
                                                       int N, int FB) {
    if ((int)blockIdx.x < FB) {
        int t = blockIdx.x * 256 + threadIdx.x;
        int stride = FB * 256;
        int s[8]; int d[8]; unsigned slot[8];
        #pragma unroll
        for (int k = 0; k < 8; ++k) {
            int e = t + k * stride;
            bool v = (e < E);
            s[k] = v ? ei[e] : -1;       // row 0: src
            d[k] = v ? ei[E + e] : 0;    // row 1: dst
        }
        #pragma unroll
        for (int k = 0; k < 8; ++k)
            slot[k] = (s[k] >= 0) ? atomicAdd(&cnt[d[k]], 1u) : 0u;
        #pragma unroll
        for (int k = 0; k < 8; ++k)
            if (s[k] >= 0 && slot[k] < CAP)
                csr[(size_t)d[k] * CAP + slot[k]] = s[k];
    } else {
        int bid = blockIdx.x - FB;
        int n = (bid * 256 + threadIdx.x) >> 6;
        int lane = threadIdx.x & 63;
        if (n >= N) return;
        float4 v = ((const float4*)x)[(size_t)n * 64 + lane];
        unsigned short* xb = xbp + (size_t)n * 384;
        xb[lane]           = 0;            // t = -1 guard
        xb[64 + lane]      = f2bf(v.x);    // t = 0
        xb[128 + lane]     = f2bf(v.y);
        xb[192 + lane]     = f2bf(v.z);
        xb[256 + lane]     = f2bf(v.w);
        xb[320 + lane]     = 0;            // t = 4 guard
    }
}

// Wave per TWO nodes; lane = channel c (ushort4 = t0..3). Interleaved inner
// loop: 2 int4 index loads + 8 cnt loads + 8 independent 512B gathers in
// flight per iter. Per-edge fp32 scale by rsqrtf(cnt[src]+1) computed inline.
__global__ __launch_bounds__(256) void gather_kernel(const ushort4* __restrict__ xsr,
                                                     const int* __restrict__ csr,
                                                     const unsigned* __restrict__ cnt,
                                                     unsigned short* __restrict__ yT,
                                                     int N) {
    int w = (blockIdx.x * 256 + threadIdx.x) >> 6;
    int lane = threadIdx.x & 63;
    int n0 = w * 2;
    if (n0 >= N) return;
    int n1 = n0 + 1;                           // N even
    unsigned deg0 = cnt[n0], deg1 = cnt[n1];
    int m0 = (int)deg0; if (m0 > CAP) m0 = CAP;
    int m1 = (int)deg1; if (m1 > CAP) m1 = CAP;
    const int4* r40 = (const int4*)(csr + (size_t)n0 * CAP);
    const int4* r41 = (const int4*)(csr + (size_t)n1 * CAP);
    float di0 = rsqrtf((float)deg0 + 1.0f);
    float di1 = rsqrtf((float)deg1 + 1.0f);
    ushort4 s0 = xsr[(size_t)n0 * 64 + lane];
    ushort4 s1 = xsr[(size_t)n1 * 64 + lane];
    float4 acc0 = make_float4(bf2f(s0.x) * di0, bf2f(s0.y) * di0,
                              bf2f(s0.z) * di0, bf2f(s0.w) * di0);
    float4 acc1 = make_float4(bf2f(s1.x) * di1, bf2f(s1.y) * di1,
                              bf2f(s1.z) * di1, bf2f(s1.w) * di1);

    int mc = (m0 < m1 ? m0 : m1) & ~3;
    int i = 0;
    for (; i < mc; i += 4) {                   // interleaved: 8 gathers in flight
        int4 a4 = r40[i >> 2];
        int4 b4 = r41[i >> 2];
        float va = rsqrtf((float)cnt[a4.x] + 1.0f);
        float vb = rsqrtf((float)cnt[a4.y] + 1.0f);
        float vc = rsqrtf((float)cnt[a4.z] + 1.0f);
        float vd = rsqrtf((float)cnt[a4.w] + 1.0f);
        float ve = rsqrtf((float)cnt[b4.x] + 1.0f);
        float vf = rsqrtf((float)cnt[b4.y] + 1.0f);
        float vg = rsqrtf((float)cnt[b4.z] + 1.0f);
        float vh = rsqrtf((float)cnt[b4.w] + 1.0f);
        ushort4 a = xsr[(size_t)a4.x * 64 + lane];
        ushort4 b = xsr[(size_t)a4.y * 64 + lane];
        ushort4 c = xsr[(size_t)a4.z * 64 + lane];
        ushort4 d = xsr[(size_t)a4.w * 64 + lane];
        ushort4 e = xsr[(size_t)b4.x * 64 + lane];
        ushort4 f = xsr[(size_t)b4.y * 64 + lane];
        ushort4 g = xsr[(size_t)b4.z * 64 + lane];
        ushort4 h = xsr[(size_t)b4.w * 64 + lane];
        acc0.x += (bf2f(a.x) * va + bf2f(b.x) * vb) + (bf2f(c.x) * vc + bf2f(d.x) * vd);
        acc0.y += (bf2f(a.y) * va + bf2f(b.y) * vb) + (bf2f(c.y) * vc + bf2f(d.y) * vd);
        acc0.z += (bf2f(a.z) * va + bf2f(b.z) * vb) + (bf2f(c.z) * vc + bf2f(d.z) * vd);
        acc0.w += (bf2f(a.w) * va + bf2f(b.w) * vb) + (bf2f(c.w) * vc + bf2f(d.w) * vd);
        acc1.x += (bf2f(e.x) * ve + bf2f(f.x) * vf) + (bf2f(g.x) * vg + bf2f(h.x) * vh);
        acc1.y += (bf2f(e.y) * ve + bf2f(f.y) * vf) + (bf2f(g.y) * vg + bf2f(h.y) * vh);
        acc1.z += (bf2f(e.z) * ve + bf2f(f.z) * vf) + (bf2f(g.z) * vg + bf2f(h.z) * vh);
        acc1.w += (bf2f(e.w) * ve + bf2f(f.w) * vf) + (bf2f(g.w) * vg + bf2f(h.w) * vh);
    }
    int j = i;
    for (; i + 4 <= m0; i += 4) {              // node0 remainder quads
        int4 a4 = r40[i >> 2];
        float va = rsqrtf((float)cnt[a4.x] + 1.0f);
        float vb = rsqrtf((float)cnt[a4.y] + 1.0f);
        float vc = rsqrtf((float)cnt[a4.z] + 1.0f);
        float vd = rsqrtf((float)cnt[a4.w] + 1.0f);
        ushort4 a = xsr[(size_t)a4.x * 64 + lane];
        ushort4 b = xsr[(size_t)a4.y * 64 + lane];
        ushort4 c = xsr[(size_t)a4.z * 64 + lane];
        ushort4 d = xsr[(size_t)a4.w * 64 + lane];
        acc0.x += (bf2f(a.x) * va + bf2f(b.x) * vb) + (bf2f(c.x) * vc + bf2f(d.x) * vd);
        acc0.y += (bf2f(a.y) * va + bf2f(b.y) * vb) + (bf2f(c.y) * vc + bf2f(d.y) * vd);
        acc0.z += (bf2f(a.z) * va + bf2f(b.z) * vb) + (bf2f(c.z) * vc + bf2f(d.z) * vd);
        acc0.w += (bf2f(a.w) * va + bf2f(b.w) * vb) + (bf2f(c.w) * vc + bf2f(d.w) * vd);
    }
    for (; i < m0; ++i) {
        int s = ((const int*)r40)[i];
        float dv = rsqrtf((float)cnt[s] + 1.0f);
        ushort4 a = xsr[(size_t)s * 64 + lane];
        acc0.x += bf2f(a.x) * dv; acc0.y += bf2f(a.y) * dv;
        acc0.z += bf2f(a.z) * dv; acc0.w += bf2f(a.w) * dv;
    }
    for (; j + 4 <= m1; j += 4) {              // node1 remainder quads
        int4 b4 = r41[j >> 2];
        float ve = rsqrtf((float)cnt[b4.x] + 1.0f);
        float vf = rsqrtf((float)cnt[b4.y] + 1.0f);
        float vg = rsqrtf((float)cnt[b4.z] + 1.0f);
        float vh = rsqrtf((float)cnt[b4.w] + 1.0f);
        ushort4 e = xsr[(size_t)b4.x * 64 + lane];
        ushort4 f = xsr[(size_t)b4.y * 64 + lane];
        ushort4 g = xsr[(size_t)b4.z * 64 + lane];
        ushort4 h = xsr[(size_t)b4.w * 64 + lane];
        acc1.x += (bf2f(e.x) * ve + bf2f(f.x) * vf) + (bf2f(g.x) * vg + bf2f(h.x) * vh);
        acc1.y += (bf2f(e.y) * ve + bf2f(f.y) * vf) + (bf2f(g.y) * vg + bf2f(h.y) * vh);
        acc1.z += (bf2f(e.z) * ve + bf2f(f.z) * vf) + (bf2f(g.z) * vg + bf2f(h.z) * vh);
        acc1.w += (bf2f(e.w) * ve + bf2f(f.w) * vf) + (bf2f(g.w) * vg + bf2f(h.w) * vh);
    }
    for (; j < m1; ++j) {
        int s = ((const int*)r41)[j];
        float dv = rsqrtf((float)cnt[s] + 1.0f);
        ushort4 e = xsr[(size_t)s * 64 + lane];
        acc1.x += bf2f(e.x) * dv; acc1.y += bf2f(e.y) * dv;
        acc1.z += bf2f(e.z) * dv; acc1.w += bf2f(e.w) * dv;
    }

    unsigned short* yp0 = yT + (size_t)n0 * 256;
    unsigned short* yp1 = yT + (size_t)n1 * 256;
    yp0[lane]       = f2bf(acc0.x * di0);      // coalesced 128B rows
    yp0[64 + lane]  = f2bf(acc0.y * di0);
    yp0[128 + lane] = f2bf(acc0.z * di0);
    yp0[192 + lane] = f2bf(acc0.w * di0);
    yp1[lane]       = f2bf(acc1.x * di1);
    yp1[64 + lane]  = f2bf(acc1.y * di1);
    yp1[128 + lane] = f2bf(acc1.z * di1);
    yp1[192 + lane] = f2bf(acc1.w * di1);
}

// MFMA node kernel. Wave = 4 groups x 4 nodes = 16 nodes. Per group: 16 M-rows
// (m = nd*4 + t), K = 256, o = 64 (4 otiles of 16).
// A[(n,t)][k]: k<64 -> yT[n][t][k]; k=b*64+c -> xbp[n][t+b-1][c] (guarded rows).
// A-frag: lane holds A[m=lane&15][k = ki*32 + (lane>>4)*8 + j], 16B contiguous.
// B-frag: lane holds W[k][o = otile*16 + (lane&15)] from Bt[o][k], 16B contiguous.
// C/D: col = lane&15 (=o-idx), row = (lane>>4)*4 + reg -> node +(lane>>4), t = reg.
__global__ __launch_bounds__(256) void node_kernel(const unsigned short* __restrict__ yT,
                                                   const unsigned short* __restrict__ xbp,
                                                   const unsigned short* __restrict__ Bt,
                                                   const float* __restrict__ bb,
                                                   float* __restrict__ out, int N) {
    int wid = (blockIdx.x * 256 + threadIdx.x) >> 6;   // global wave id
    int lane = threadIdx.x & 63;
    int base = wid * 16;                               // first node of this wave
    if (base + 16 > N) return;                         // N % 16 == 0
    int h = lane >> 4;          // quad
    int m = lane & 15;
    int nd = m >> 2, t = m & 3;

    const unsigned short* yp[4];
    const unsigned short* xp[4];
    #pragma unroll
    for (int g = 0; g < 4; ++g) {
        int node = base + g * 4 + nd;
        yp[g] = yT + (size_t)node * 256 + t * 64;
        xp[g] = xbp + (size_t)node * 384 + t * 64;
    }

    f32x4 acc[4][4];
    #pragma unroll
    for (int g = 0; g < 4; ++g)
        #pragma unroll
        for (int ot = 0; ot < 4; ++ot)
            acc[g][ot] = (f32x4){0.f, 0.f, 0.f, 0.f};

    #pragma unroll
    for (int ki = 0; ki < 8; ++ki) {
        int b = ki >> 1;                       // 64-wide K-block
        int c0 = (ki & 1) * 32 + h * 8;        // offset within block
        int kof = ki * 32 + h * 8;
        bf16x8 bf[4];
        #pragma unroll
        for (int ot = 0; ot < 4; ++ot)
            bf[ot] = *(const bf16x8*)(Bt + (size_t)(ot * 16 + m) * 256 + kof);
        bf16x8 af[4];
        #pragma unroll
        for (int g = 0; g < 4; ++g) {
            const unsigned short* ap = (b == 0) ? (yp[g] + c0)
                                                : (xp[g] + (b - 1) * 64 + c0);
            af[g] = *(const bf16x8*)ap;
        }
        #pragma unroll
        for (int g = 0; g < 4; ++g) {
            acc[g][0] = __builtin_amdgcn_mfma_f32_16x16x32_bf16(af[g], bf[0], acc[g][0], 0, 0, 0);
            acc[g][1] = __builtin_amdgcn_mfma_f32_16x16x32_bf16(af[g], bf[1], acc[g][1], 0, 0, 0);
            acc[g][2] = __builtin_amdgcn_mfma_f32_16x16x32_bf16(af[g], bf[2], acc[g][2], 0, 0, 0);
            acc[g][3] = __builtin_amdgcn_mfma_f32_16x16x32_bf16(af[g], bf[3], acc[g][3], 0, 0, 0);
        }
    }

    float4* out4 = (float4*)out;               // out[n][o][t], float4 over t
    #pragma unroll
    for (int g = 0; g < 4; ++g) {
        int nn = base + g * 4 + h;             // output node for this lane
        #pragma unroll
        for (int ot = 0; ot < 4; ++ot) {
            int o = ot * 16 + m;
            float bias = bb[o];
            out4[(size_t)nn * 64 + o] = make_float4(acc[g][ot][0] + bias,
                                                    acc[g][ot][1] + bias,
                                                    acc[g][ot][2] + bias,
                                                    acc[g][ot][3] + bias);
        }
    }
}

extern "C" void kernel_launch(void* const* d_in, const int* in_sizes, int n_in,
                              void* d_out, int out_size, void* d_ws, size_t ws_size,
                              hipStream_t stream) {
    const float* x  = (const float*)d_in[0];
    const int*   ei = (const int*)d_in[1];
    const float* Wg = (const float*)d_in[2];
    const float* bg = (const float*)d_in[3];
    const float* Wt = (const float*)d_in[4];
    const float* bt = (const float*)d_in[5];
    float* out = (float*)d_out;

    int N = in_sizes[0] / 256;   // 50000
    int E = in_sizes[1] / 2;     // 800000

    // workspace layout (256B-aligned):
    size_t off = 0;
    auto alloc = [&](size_t bytes) { size_t o = off; off += (bytes + 255) & ~(size_t)255; return o; };
    char* ws = (char*)d_ws;
    unsigned*       cnt  = (unsigned*)(ws + alloc((size_t)N * 4));
    unsigned short* Bt   = (unsigned short*)(ws + alloc(64 * 256 * 2));
    float*          bb   = (float*)(ws + alloc(64 * 4));
    int*            csr  = (int*)(ws + alloc((size_t)N * CAP * 4));
    ushort4*        xsr  = (ushort4*)(ws + alloc((size_t)N * 256 * 2));
    unsigned short* xbp  = (unsigned short*)(ws + alloc((size_t)N * 384 * 2));
    unsigned short* yT   = (unsigned short*)(ws + alloc((size_t)N * 256 * 2));
    // total ~103 MB

    int XB = (N + 3) / 4;                      // 12500 wave-per-node blocks
    zero_pack_kernel<<<XB, 256, 0, stream>>>(cnt, N, Wg, Wt, bg, bt, Bt, bb, x, xsr);
    int FB = (E + 2047) / 2048;                // 391 fill blocks (8 edges/thread)
    fill_xbp_kernel<<<FB + XB, 256, 0, stream>>>(ei, cnt, csr, E, x, xbp, N, FB);
    int gw = (N + 1) / 2;                      // 25000 waves, 2 nodes each
    gather_kernel<<<(gw + 3) / 4, 256, 0, stream>>>(xsr, csr, cnt, yT, N);
    int waves = N / 16;                        // 3125
    node_kernel<<<(waves + 3) / 4, 256, 0, stream>>>(yT, xbp, Bt, bb, out, N);
}